// Round 6
// baseline (6046.267 us; speedup 1.0000x reference)
//
#include <hip/hip_runtime.h>
#include <hip/hip_bf16.h>

#define BB 512
#define SS 512
#define EE 128
#define HH 256
#define VV 128
#define G4H 1024
#define TSL 64              // rec1 time-slice length
#define NSEG (SS / TSL)     // 8

using bf16 = __bf16;
typedef __attribute__((ext_vector_type(8))) __bf16 bf16x8;
typedef __attribute__((ext_vector_type(4))) float f32x4;

__device__ __forceinline__ float rcpf(float x) { return __builtin_amdgcn_rcpf(x); }
__device__ __forceinline__ float sigf(float x) { return rcpf(1.0f + __expf(-x)); }
__device__ __forceinline__ float tanhf_(float x) {
  float e = __expf(-2.0f * fabsf(x));
  float r = (1.0f - e) * rcpf(1.0f + e);
  return x < 0.0f ? -r : r;
}
__device__ __forceinline__ bf16x8 cvt8(const float* __restrict__ s) {
  bf16x8 f;
  #pragma unroll
  for (int j = 0; j < 8; ++j) f[j] = (bf16)s[j];
  return f;
}
__device__ __forceinline__ float bf2f(unsigned short u) {
  return __uint_as_float(((unsigned)u) << 16);
}

// ---------------------------------------------------------------------------
// x dtype sniffer (validated R4): odd 32-bit words all zero <=> int64.
// ---------------------------------------------------------------------------
__global__ void detect_kernel(const int* __restrict__ x, int* __restrict__ flag) {
  const int i = blockIdx.x * 256 + threadIdx.x;
  if (x[2 * i + 1] != 0) atomicOr(flag, 1);
}

// ---------------------------------------------------------------------------
// table[v][g] = dot(emb[v,:], Wi0[g,:]) + bi0[g] + bh0[g]   (fp32, 128x1024)
// ---------------------------------------------------------------------------
__global__ __launch_bounds__(256)
void table_kernel(const float* __restrict__ emb, const float* __restrict__ Wi,
                  const float* __restrict__ bi, const float* __restrict__ bh,
                  float* __restrict__ table) {
  const int g = blockIdx.x * 256 + threadIdx.x;
  const int v = blockIdx.y;
  float s = bi[g] + bh[g];
  const float* er = emb + v * EE;
  const float* wr = Wi + (size_t)g * EE;
  #pragma unroll 4
  for (int e = 0; e < EE; ++e) s += er[e] * wr[e];
  table[v * G4H + g] = s;
}

// ---------------------------------------------------------------------------
// MFMA recurrence, layer 0. 64 WGs x 512 thr; WG owns 8 batch rows (M-tile
// half-empty: trades wasted MFMA lanes for 2x CUs + halved gather/conflicts).
// Wave w owns hidden cols [32w,32w+32). f,i,g gates in VGPRs, o-gate in LDS.
// Software prefetch: x 2 steps ahead, table row values 1 step ahead.
// ---------------------------------------------------------------------------
__global__ __launch_bounds__(512, 2)
void rec0_kernel(const int* __restrict__ x, const int* __restrict__ flagp,
                 const float* __restrict__ Wh, const float* __restrict__ table,
                 bf16* __restrict__ h1) {
  __shared__ bf16 hbuf[2][4096];     // fragment-major h state
  __shared__ bf16x8 wlds[8192];      // 128KB o-gate weights
  const int tid = threadIdx.x, w = tid >> 6, l = tid & 63, lg = l >> 4, ln = l & 15;
  const int b0 = blockIdx.x * 8, hb = w * 32;
  const int is32 = *flagp;

  bf16x8 Wf[6][8];
  #pragma unroll
  for (int qj = 0; qj < 6; ++qj) {
    const int n = (qj >> 1) * HH + hb + 16 * (qj & 1) + ln;
    #pragma unroll
    for (int kc = 0; kc < 8; ++kc) Wf[qj][kc] = cvt8(Wh + (size_t)n * HH + kc * 32 + lg * 8);
  }
  #pragma unroll
  for (int j = 0; j < 2; ++j) {
    const int n = 3 * HH + hb + 16 * j + ln;
    #pragma unroll
    for (int kc = 0; kc < 8; ++kc)
      wlds[((w * 2 + j) * 8 + kc) * 64 + ln * 4 + lg] = cvt8(Wh + (size_t)n * HH + kc * 32 + lg * 8);
  }
  { bf16x8 z = {}; ((bf16x8*)hbuf[0])[tid] = z; }
  float c[2][4] = {};

  // batch row per r (clamped: rows >=8 are padding, loads read row b0)
  long xrow[4];
  #pragma unroll
  for (int r = 0; r < 4; ++r) {
    const int m = lg * 4 + r;
    xrow[r] = (long)(b0 + (m < 8 ? m : 0)) * SS;
  }
  // prologue: gather t=0 (serial, once) + x for t=1
  int nidx[4];
  float ptab[32];
  #pragma unroll
  for (int r = 0; r < 4; ++r) {
    const long xi = xrow[r] + 0;
    const int idx = x[is32 ? xi : 2 * xi] & 127;
    #pragma unroll
    for (int q = 0; q < 4; ++q)
      #pragma unroll
      for (int j = 0; j < 2; ++j)
        ptab[(q * 2 + j) * 4 + r] = table[idx * G4H + q * HH + hb + 16 * j + ln];
  }
  #pragma unroll
  for (int r = 0; r < 4; ++r) {
    const long xi = xrow[r] + 1;
    nidx[r] = x[is32 ? xi : 2 * xi] & 127;
  }
  __syncthreads();

  #pragma unroll 1
  for (int t = 0; t < SS; ++t) {
    const int p = t & 1;
    // 1. acc init from prefetched table values
    f32x4 acc[4][2];
    #pragma unroll
    for (int q = 0; q < 4; ++q)
      #pragma unroll
      for (int j = 0; j < 2; ++j)
        #pragma unroll
        for (int r = 0; r < 4; ++r) acc[q][j][r] = ptab[(q * 2 + j) * 4 + r];
    // 2. prefetch table values for t+1 (indices already resident)
    if (t + 1 < SS) {
      #pragma unroll
      for (int q = 0; q < 4; ++q)
        #pragma unroll
        for (int j = 0; j < 2; ++j)
          #pragma unroll
          for (int r = 0; r < 4; ++r)
            ptab[(q * 2 + j) * 4 + r] = table[nidx[r] * G4H + q * HH + hb + 16 * j + ln];
    }
    // 3. prefetch x indices for t+2
    if (t + 2 < SS) {
      #pragma unroll
      for (int r = 0; r < 4; ++r) {
        const long xi = xrow[r] + (t + 2);
        nidx[r] = x[is32 ? xi : 2 * xi] & 127;
      }
    }
    // 4. MFMA: gates += h_{t-1} @ Wh^T
    #pragma unroll
    for (int kc = 0; kc < 8; ++kc) {
      bf16x8 a = ((const bf16x8*)hbuf[p])[kc * 64 + ln * 4 + lg];
      #pragma unroll
      for (int qj = 0; qj < 6; ++qj)
        acc[qj >> 1][qj & 1] = __builtin_amdgcn_mfma_f32_16x16x32_bf16(
            a, Wf[qj][kc], acc[qj >> 1][qj & 1], 0, 0, 0);
      #pragma unroll
      for (int j = 0; j < 2; ++j) {
        bf16x8 bw = wlds[((w * 2 + j) * 8 + kc) * 64 + ln * 4 + lg];
        acc[3][j] = __builtin_amdgcn_mfma_f32_16x16x32_bf16(a, bw, acc[3][j], 0, 0, 0);
      }
    }
    // 5. nonlinearity + state update (rows >= 8 computed but discarded)
    #pragma unroll
    for (int j = 0; j < 2; ++j)
      #pragma unroll
      for (int r = 0; r < 4; ++r) {
        const float fg = sigf(acc[0][j][r]);
        const float ig = sigf(acc[1][j][r]);
        const float gg = tanhf_(acc[2][j][r]);
        const float og = sigf(acc[3][j][r]);
        const float cc = fg * c[j][r] + ig * gg;
        c[j][r] = cc;
        const bf16 hv = (bf16)(og * tanhf_(cc));
        const int m = lg * 4 + r;
        if (m < 8) {
          hbuf[p ^ 1][(w * 64 + m * 4 + 2 * j + (ln >> 3)) * 8 + (ln & 7)] = hv;
          h1[((size_t)(b0 + m) * SS + t) * HH + hb + 16 * j + ln] = hv;
        }
      }
    __syncthreads();
  }
}

// ---------------------------------------------------------------------------
// MFMA recurrence, layer 1, one time-slice. acc init from prefetched xg.
// ---------------------------------------------------------------------------
__global__ __launch_bounds__(512, 2)
void rec1_kernel(const bf16* __restrict__ xg, const float* __restrict__ Wh,
                 bf16* __restrict__ hreg, float* __restrict__ cws, int t0) {
  __shared__ bf16 hbuf[2][4096];
  __shared__ bf16x8 wlds[8192];
  const int tid = threadIdx.x, w = tid >> 6, l = tid & 63, lg = l >> 4, ln = l & 15;
  const int b0 = blockIdx.x * 8, hb = w * 32;
  const unsigned short* xgu = (const unsigned short*)xg;

  bf16x8 Wf[6][8];
  #pragma unroll
  for (int qj = 0; qj < 6; ++qj) {
    const int n = (qj >> 1) * HH + hb + 16 * (qj & 1) + ln;
    #pragma unroll
    for (int kc = 0; kc < 8; ++kc) Wf[qj][kc] = cvt8(Wh + (size_t)n * HH + kc * 32 + lg * 8);
  }
  #pragma unroll
  for (int j = 0; j < 2; ++j) {
    const int n = 3 * HH + hb + 16 * j + ln;
    #pragma unroll
    for (int kc = 0; kc < 8; ++kc)
      wlds[((w * 2 + j) * 8 + kc) * 64 + ln * 4 + lg] = cvt8(Wh + (size_t)n * HH + kc * 32 + lg * 8);
  }
  // per-r clamped batch row
  size_t brow[4];
  #pragma unroll
  for (int r = 0; r < 4; ++r) {
    const int m = lg * 4 + r;
    brow[r] = (size_t)(b0 + (m < 8 ? m : 0));
  }
  float c[2][4];
  if (t0 == 0) {
    #pragma unroll
    for (int j = 0; j < 2; ++j)
      #pragma unroll
      for (int r = 0; r < 4; ++r) c[j][r] = 0.f;
    bf16x8 z = {};
    ((bf16x8*)hbuf[0])[tid] = z;
  } else {
    #pragma unroll
    for (int j = 0; j < 2; ++j)
      #pragma unroll
      for (int r = 0; r < 4; ++r) {
        const int m = lg * 4 + r, col = hb + 16 * j + ln;
        c[j][r] = cws[brow[r] * HH + col];
        const bf16 hv = (m < 8)
            ? hreg[(brow[r] * SS + (t0 - 1)) * HH + col] : (bf16)0.0f;
        hbuf[0][(w * 64 + m * 4 + 2 * j + (ln >> 3)) * 8 + (ln & 7)] = hv;
      }
  }
  // prologue prefetch: xg for tt=0
  unsigned short pxg[32];
  #pragma unroll
  for (int q = 0; q < 4; ++q)
    #pragma unroll
    for (int j = 0; j < 2; ++j)
      #pragma unroll
      for (int r = 0; r < 4; ++r)
        pxg[(q * 2 + j) * 4 + r] =
            xgu[(brow[r] * TSL + 0) * G4H + q * HH + hb + 16 * j + ln];
  __syncthreads();

  #pragma unroll 1
  for (int tt = 0; tt < TSL; ++tt) {
    const int t = t0 + tt, p = tt & 1;
    f32x4 acc[4][2];
    #pragma unroll
    for (int q = 0; q < 4; ++q)
      #pragma unroll
      for (int j = 0; j < 2; ++j)
        #pragma unroll
        for (int r = 0; r < 4; ++r) acc[q][j][r] = bf2f(pxg[(q * 2 + j) * 4 + r]);
    if (tt + 1 < TSL) {
      #pragma unroll
      for (int q = 0; q < 4; ++q)
        #pragma unroll
        for (int j = 0; j < 2; ++j)
          #pragma unroll
          for (int r = 0; r < 4; ++r)
            pxg[(q * 2 + j) * 4 + r] =
                xgu[(brow[r] * TSL + (tt + 1)) * G4H + q * HH + hb + 16 * j + ln];
    }
    #pragma unroll
    for (int kc = 0; kc < 8; ++kc) {
      bf16x8 a = ((const bf16x8*)hbuf[p])[kc * 64 + ln * 4 + lg];
      #pragma unroll
      for (int qj = 0; qj < 6; ++qj)
        acc[qj >> 1][qj & 1] = __builtin_amdgcn_mfma_f32_16x16x32_bf16(
            a, Wf[qj][kc], acc[qj >> 1][qj & 1], 0, 0, 0);
      #pragma unroll
      for (int j = 0; j < 2; ++j) {
        bf16x8 bw = wlds[((w * 2 + j) * 8 + kc) * 64 + ln * 4 + lg];
        acc[3][j] = __builtin_amdgcn_mfma_f32_16x16x32_bf16(a, bw, acc[3][j], 0, 0, 0);
      }
    }
    #pragma unroll
    for (int j = 0; j < 2; ++j)
      #pragma unroll
      for (int r = 0; r < 4; ++r) {
        const float fg = sigf(acc[0][j][r]);
        const float ig = sigf(acc[1][j][r]);
        const float gg = tanhf_(acc[2][j][r]);
        const float og = sigf(acc[3][j][r]);
        const float cc = fg * c[j][r] + ig * gg;
        c[j][r] = cc;
        const bf16 hv = (bf16)(og * tanhf_(cc));
        const int m = lg * 4 + r;
        if (m < 8) {
          hbuf[p ^ 1][(w * 64 + m * 4 + 2 * j + (ln >> 3)) * 8 + (ln & 7)] = hv;
          hreg[((size_t)(b0 + m) * SS + t) * HH + hb + 16 * j + ln] = hv;
        }
      }
    __syncthreads();
  }
  #pragma unroll
  for (int j = 0; j < 2; ++j)
    #pragma unroll
    for (int r = 0; r < 4; ++r) {
      const int m = lg * 4 + r;
      if (m < 8) cws[(size_t)(b0 + m) * HH + hb + 16 * j + ln] = c[j][r];
    }
}

// ---------------------------------------------------------------------------
// Tiled GEMM 128x128, K=256, 8 waves, XOR-swizzled LDS (conflict-free-ish).
// AB == 1: xg slice (bf16 out, bias bi+bh); AB == 0: proj (fp32 out, bias bg).
// A rows: slice rows b*TSL+tt -> h1[b][t0+tt] (xg) or flat rows (proj).
// ---------------------------------------------------------------------------
template <int OUT_BF16>
__global__ __launch_bounds__(512)
void gemm_kernel(const bf16* __restrict__ A, const float* __restrict__ W,
                 const float* __restrict__ bias0, const float* __restrict__ bias1,
                 void* __restrict__ out, int t0, int NCOL) {
  __shared__ bf16x8 alds[4096];   // 128 rows x 32 granules(16B)
  __shared__ bf16x8 blds[4096];
  const int tid = threadIdx.x, w = tid >> 6, l = tid & 63, lg = l >> 4, ln = l & 15;
  const int wm = w & 1, wn = w >> 1;
  const int R0 = blockIdx.x * 128, N0 = blockIdx.y * 128;
  {
    const int row = tid >> 2, seg = tid & 3;   // 4 thr/row, 64 cols each
    const bf16* asrc;
    if (OUT_BF16) {
      const int R = R0 + row;
      asrc = A + ((size_t)(R >> 6) * SS + t0 + (R & 63)) * HH + seg * 64;
    } else {
      asrc = A + ((size_t)R0 + row) * HH + seg * 64;
    }
    #pragma unroll
    for (int k = 0; k < 8; ++k) {
      const int g = seg * 8 + k;
      alds[row * 32 + (g ^ (row & 7))] = *(const bf16x8*)(asrc + k * 8);
    }
    const float* bsrc = W + (size_t)(N0 + row) * HH + seg * 64;
    #pragma unroll
    for (int k = 0; k < 8; ++k) {
      const int g = seg * 8 + k;
      blds[row * 32 + (g ^ (row & 7))] = cvt8(bsrc + k * 8);
    }
  }
  __syncthreads();
  f32x4 acc[4][2] = {};
  #pragma unroll
  for (int kc = 0; kc < 8; ++kc) {
    bf16x8 bfr[2];
    #pragma unroll
    for (int nt = 0; nt < 2; ++nt) {
      const int row = wn * 32 + nt * 16 + ln;
      bfr[nt] = blds[row * 32 + ((kc * 4 + lg) ^ (row & 7))];
    }
    #pragma unroll
    for (int mt = 0; mt < 4; ++mt) {
      const int row = wm * 64 + mt * 16 + ln;
      bf16x8 a = alds[row * 32 + ((kc * 4 + lg) ^ (row & 7))];
      #pragma unroll
      for (int nt = 0; nt < 2; ++nt)
        acc[mt][nt] = __builtin_amdgcn_mfma_f32_16x16x32_bf16(a, bfr[nt], acc[mt][nt], 0, 0, 0);
    }
  }
  #pragma unroll
  for (int nt = 0; nt < 2; ++nt) {
    const int n = N0 + wn * 32 + nt * 16 + ln;
    const float bv = bias0[n] + (bias1 ? bias1[n] : 0.f);
    #pragma unroll
    for (int mt = 0; mt < 4; ++mt)
      #pragma unroll
      for (int r = 0; r < 4; ++r) {
        const size_t row = (size_t)R0 + wm * 64 + mt * 16 + lg * 4 + r;
        if (OUT_BF16) ((bf16*)out)[row * NCOL + n] = (bf16)(acc[mt][nt][r] + bv);
        else          ((float*)out)[row * NCOL + n] = acc[mt][nt][r] + bv;
      }
  }
}

extern "C" void kernel_launch(void* const* d_in, const int* in_sizes, int n_in,
                              void* d_out, int out_size, void* d_ws, size_t ws_size,
                              hipStream_t stream) {
  const int*   x   = (const int*)d_in[0];
  const float* emb = (const float*)d_in[1];
  const float* Wi0 = (const float*)d_in[2];
  const float* bi0 = (const float*)d_in[3];
  const float* Wh0 = (const float*)d_in[4];
  const float* bh0 = (const float*)d_in[5];
  const float* Wi1 = (const float*)d_in[6];
  const float* bi1 = (const float*)d_in[7];
  const float* Wh1 = (const float*)d_in[8];
  const float* bh1 = (const float*)d_in[9];
  const float* Wg  = (const float*)d_in[10];
  const float* bg  = (const float*)d_in[11];

  // ws: [flag 256B][table fp32 512KB][hreg bf16 128MB]  (proven available)
  char* ws = (char*)d_ws;
  int*   flag  = (int*)ws;
  float* table = (float*)(ws + 256);
  bf16*  hreg  = (bf16*)(ws + 256 + (size_t)VV * G4H * sizeof(float));
  const size_t need = 256 + (size_t)VV * G4H * sizeof(float)
                    + (size_t)BB * SS * HH * sizeof(bf16);
  if (ws_size < need) return;

  // d_out as scratch until proj: [xg slice 67.1MB][cws 512KB]
  bf16*  xg  = (bf16*)d_out;
  float* cws = (float*)((char*)d_out + (size_t)BB * TSL * G4H * sizeof(bf16));

  hipMemsetAsync(flag, 0, sizeof(int), stream);
  detect_kernel<<<dim3(8), dim3(256), 0, stream>>>(x, flag);
  table_kernel<<<dim3(4, 128), dim3(256), 0, stream>>>(emb, Wi0, bi0, bh0, table);
  rec0_kernel<<<dim3(BB / 8), dim3(512), 0, stream>>>(x, flag, Wh0, table, hreg);
  for (int s = 0; s < NSEG; ++s) {
    const int t0 = s * TSL;
    gemm_kernel<1><<<dim3(BB * TSL / 128, G4H / 128), dim3(512), 0, stream>>>(
        hreg, Wi1, bi1, bh1, xg, t0, G4H);
    rec1_kernel<<<dim3(BB / 8), dim3(512), 0, stream>>>(xg, Wh1, hreg, cws, t0);
  }
  gemm_kernel<0><<<dim3(BB * SS / 128, VV / 128), dim3(512), 0, stream>>>(
      hreg, Wg, bg, nullptr, d_out, 0, VV);
}

// Round 8
// 5381.945 us; speedup vs baseline: 1.1234x; 1.1234x over previous
//
#include <hip/hip_runtime.h>
#include <hip/hip_bf16.h>

#define BB 512
#define SS 512
#define EE 128
#define HH 256
#define VV 128
#define G4H 1024
#define TSL 64              // rec1 time-slice length
#define NSEG (SS / TSL)     // 8

using bf16 = __bf16;
typedef __attribute__((ext_vector_type(8))) __bf16 bf16x8;
typedef __attribute__((ext_vector_type(4))) float f32x4;

__device__ __forceinline__ float rcpf(float x) { return __builtin_amdgcn_rcpf(x); }
__device__ __forceinline__ float exp2f_(float x) { return __builtin_amdgcn_exp2f(x); }
// sigma(x) = 1/(1+2^(-x*log2e));  tanh(x) = 2*sigma(2x)-1  (branch-free)
__device__ __forceinline__ float sigf(float x) {
  return rcpf(1.0f + exp2f_(-1.442695041f * x));
}
__device__ __forceinline__ float tanh_(float x) {
  return 2.0f * rcpf(1.0f + exp2f_(-2.885390082f * x)) - 1.0f;
}
__device__ __forceinline__ bf16x8 cvt8(const float* __restrict__ s) {
  bf16x8 f;
  #pragma unroll
  for (int j = 0; j < 8; ++j) f[j] = (bf16)s[j];
  return f;
}
__device__ __forceinline__ float bf2f(unsigned short u) {
  return __uint_as_float(((unsigned)u) << 16);
}

// ---------------------------------------------------------------------------
// x dtype sniffer (validated R4): odd 32-bit words all zero <=> int64.
// ---------------------------------------------------------------------------
__global__ void detect_kernel(const int* __restrict__ x, int* __restrict__ flag) {
  const int i = blockIdx.x * 256 + threadIdx.x;
  if (x[2 * i + 1] != 0) atomicOr(flag, 1);
}

// ---------------------------------------------------------------------------
// Gate-interleaved bf16 table: table[v][u*4+q] = emb[v,:].Wi0[q*256+u,:]
//                                               + bi0[g] + bh0[g]
// ---------------------------------------------------------------------------
__global__ __launch_bounds__(256)
void table_kernel(const float* __restrict__ emb, const float* __restrict__ Wi,
                  const float* __restrict__ bi, const float* __restrict__ bh,
                  unsigned short* __restrict__ table) {
  const int g = blockIdx.x * 256 + threadIdx.x;  // 0..1023
  const int v = blockIdx.y;                      // 0..127
  float s = bi[g] + bh[g];
  const float* er = emb + v * EE;
  const float* wr = Wi + (size_t)g * EE;
  #pragma unroll 4
  for (int e = 0; e < EE; ++e) s += er[e] * wr[e];
  const bf16 b = (bf16)s;
  table[v * G4H + (g & 255) * 4 + (g >> 8)] = *(const unsigned short*)&b;
}

// ---------------------------------------------------------------------------
// MFMA recurrence, layer 0. 32 WGs x 512 thr (8 waves). 16 batch rows/WG.
// Wave w owns hidden cols [32w,32w+32): f,i,g gates (6 tiles) in VGPRs,
// o-gate (2 tiles) in LDS. h state fragment-major in LDS with XOR swizzle
// (write g ^= m>>2, read g ^= ln>>2) -> conflict-free h writes.
// acc starts at 0; table contribution added in epilogue so the 8x8B gather
// issued at step-top hides under the MFMA loop.
// NOTE: __launch_bounds__(512) only -> 256-VGPR cap, weights stay resident.
// ---------------------------------------------------------------------------
__global__ __launch_bounds__(512)
void rec0_kernel(const int* __restrict__ x, const int* __restrict__ flagp,
                 const float* __restrict__ Wh,
                 const unsigned short* __restrict__ table,
                 bf16* __restrict__ h1) {
  __shared__ bf16 hbuf[2][4096];
  __shared__ bf16x8 wlds[8192];      // 128KB o-gate weights
  const int tid = threadIdx.x, w = tid >> 6, l = tid & 63, lg = l >> 4, ln = l & 15;
  const int b0 = blockIdx.x * 16, hb = w * 32;
  const int is32 = *flagp;

  bf16x8 Wf[6][8];
  #pragma unroll
  for (int qj = 0; qj < 6; ++qj) {
    const int n = (qj >> 1) * HH + hb + 16 * (qj & 1) + ln;
    #pragma unroll
    for (int kc = 0; kc < 8; ++kc) Wf[qj][kc] = cvt8(Wh + (size_t)n * HH + kc * 32 + lg * 8);
  }
  #pragma unroll
  for (int j = 0; j < 2; ++j) {
    const int n = 3 * HH + hb + 16 * j + ln;
    #pragma unroll
    for (int kc = 0; kc < 8; ++kc)
      wlds[((w * 2 + j) * 8 + kc) * 64 + ln * 4 + lg] = cvt8(Wh + (size_t)n * HH + kc * 32 + lg * 8);
  }
  { bf16x8 z = {}; ((bf16x8*)hbuf[0])[tid] = z; }
  float c[2][4] = {};

  // x indices for t=0
  int idx[4];
  #pragma unroll
  for (int r = 0; r < 4; ++r) {
    const long xi = (long)(b0 + lg * 4 + r) * SS;
    idx[r] = x[is32 ? xi : 2 * xi] & 127;
  }
  __syncthreads();

  #pragma unroll 1
  for (int t = 0; t < SS; ++t) {
    const int p = t & 1;
    // issue table gather for step t (consumed in epilogue)
    ushort4 tj[4][2];
    #pragma unroll
    for (int r = 0; r < 4; ++r) {
      const unsigned short* base = table + (size_t)idx[r] * G4H + (hb + ln) * 4;
      tj[r][0] = *(const ushort4*)base;
      tj[r][1] = *(const ushort4*)(base + 64);
    }
    // prefetch x for t+1
    if (t + 1 < SS) {
      #pragma unroll
      for (int r = 0; r < 4; ++r) {
        const long xi = (long)(b0 + lg * 4 + r) * SS + (t + 1);
        idx[r] = x[is32 ? xi : 2 * xi] & 127;
      }
    }
    // MFMA from zero: acc = h_{t-1} @ Wh^T
    f32x4 acc[4][2] = {};
    #pragma unroll
    for (int kc = 0; kc < 8; ++kc) {
      bf16x8 a = ((const bf16x8*)hbuf[p])[(kc * 64 + ln * 4 + lg) ^ (ln >> 2)];
      #pragma unroll
      for (int qj = 0; qj < 6; ++qj)
        acc[qj >> 1][qj & 1] = __builtin_amdgcn_mfma_f32_16x16x32_bf16(
            a, Wf[qj][kc], acc[qj >> 1][qj & 1], 0, 0, 0);
      #pragma unroll
      for (int j = 0; j < 2; ++j) {
        bf16x8 bw = wlds[((w * 2 + j) * 8 + kc) * 64 + ln * 4 + lg];
        acc[3][j] = __builtin_amdgcn_mfma_f32_16x16x32_bf16(a, bw, acc[3][j], 0, 0, 0);
      }
    }
    // epilogue: add table contribution, nonlinearity, state update
    #pragma unroll
    for (int j = 0; j < 2; ++j)
      #pragma unroll
      for (int r = 0; r < 4; ++r) {
        const float fg = sigf(acc[0][j][r] + bf2f(tj[r][j].x));
        const float ig = sigf(acc[1][j][r] + bf2f(tj[r][j].y));
        const float gg = tanh_(acc[2][j][r] + bf2f(tj[r][j].z));
        const float og = sigf(acc[3][j][r] + bf2f(tj[r][j].w));
        const float cc = fg * c[j][r] + ig * gg;
        c[j][r] = cc;
        const bf16 hv = (bf16)(og * tanh_(cc));
        const int m = lg * 4 + r;
        const int gidx = (w * 64 + m * 4 + 2 * j + (ln >> 3)) ^ (m >> 2);
        hbuf[p ^ 1][gidx * 8 + (ln & 7)] = hv;
        h1[((size_t)(b0 + m) * SS + t) * HH + hb + 16 * j + ln] = hv;
      }
    __syncthreads();
  }
}

// ---------------------------------------------------------------------------
// MFMA recurrence, layer 1, one time-slice [t0,t0+TSL). Same structure;
// gate init gathered from gate-interleaved bf16 xg (includes bi1+bh1).
// ---------------------------------------------------------------------------
__global__ __launch_bounds__(512)
void rec1_kernel(const unsigned short* __restrict__ xg, const float* __restrict__ Wh,
                 bf16* __restrict__ hreg, float* __restrict__ cws, int t0) {
  __shared__ bf16 hbuf[2][4096];
  __shared__ bf16x8 wlds[8192];
  const int tid = threadIdx.x, w = tid >> 6, l = tid & 63, lg = l >> 4, ln = l & 15;
  const int b0 = blockIdx.x * 16, hb = w * 32;

  bf16x8 Wf[6][8];
  #pragma unroll
  for (int qj = 0; qj < 6; ++qj) {
    const int n = (qj >> 1) * HH + hb + 16 * (qj & 1) + ln;
    #pragma unroll
    for (int kc = 0; kc < 8; ++kc) Wf[qj][kc] = cvt8(Wh + (size_t)n * HH + kc * 32 + lg * 8);
  }
  #pragma unroll
  for (int j = 0; j < 2; ++j) {
    const int n = 3 * HH + hb + 16 * j + ln;
    #pragma unroll
    for (int kc = 0; kc < 8; ++kc)
      wlds[((w * 2 + j) * 8 + kc) * 64 + ln * 4 + lg] = cvt8(Wh + (size_t)n * HH + kc * 32 + lg * 8);
  }
  float c[2][4];
  if (t0 == 0) {
    #pragma unroll
    for (int j = 0; j < 2; ++j)
      #pragma unroll
      for (int r = 0; r < 4; ++r) c[j][r] = 0.f;
    bf16x8 z = {};
    ((bf16x8*)hbuf[0])[tid] = z;
  } else {
    #pragma unroll
    for (int j = 0; j < 2; ++j)
      #pragma unroll
      for (int r = 0; r < 4; ++r) {
        const int m = lg * 4 + r, col = hb + 16 * j + ln;
        c[j][r] = cws[(size_t)(b0 + m) * HH + col];
        const bf16 hv = hreg[((size_t)(b0 + m) * SS + (t0 - 1)) * HH + col];
        const int gidx = (w * 64 + m * 4 + 2 * j + (ln >> 3)) ^ (m >> 2);
        hbuf[0][gidx * 8 + (ln & 7)] = hv;
      }
  }
  __syncthreads();

  #pragma unroll 1
  for (int tt = 0; tt < TSL; ++tt) {
    const int t = t0 + tt, p = tt & 1;
    // issue xg gather (addresses data-independent)
    ushort4 tj[4][2];
    #pragma unroll
    for (int r = 0; r < 4; ++r) {
      const unsigned short* base =
          xg + ((size_t)(b0 + lg * 4 + r) * TSL + tt) * G4H + (hb + ln) * 4;
      tj[r][0] = *(const ushort4*)base;
      tj[r][1] = *(const ushort4*)(base + 64);
    }
    f32x4 acc[4][2] = {};
    #pragma unroll
    for (int kc = 0; kc < 8; ++kc) {
      bf16x8 a = ((const bf16x8*)hbuf[p])[(kc * 64 + ln * 4 + lg) ^ (ln >> 2)];
      #pragma unroll
      for (int qj = 0; qj < 6; ++qj)
        acc[qj >> 1][qj & 1] = __builtin_amdgcn_mfma_f32_16x16x32_bf16(
            a, Wf[qj][kc], acc[qj >> 1][qj & 1], 0, 0, 0);
      #pragma unroll
      for (int j = 0; j < 2; ++j) {
        bf16x8 bw = wlds[((w * 2 + j) * 8 + kc) * 64 + ln * 4 + lg];
        acc[3][j] = __builtin_amdgcn_mfma_f32_16x16x32_bf16(a, bw, acc[3][j], 0, 0, 0);
      }
    }
    #pragma unroll
    for (int j = 0; j < 2; ++j)
      #pragma unroll
      for (int r = 0; r < 4; ++r) {
        const float fg = sigf(acc[0][j][r] + bf2f(tj[r][j].x));
        const float ig = sigf(acc[1][j][r] + bf2f(tj[r][j].y));
        const float gg = tanh_(acc[2][j][r] + bf2f(tj[r][j].z));
        const float og = sigf(acc[3][j][r] + bf2f(tj[r][j].w));
        const float cc = fg * c[j][r] + ig * gg;
        c[j][r] = cc;
        const bf16 hv = (bf16)(og * tanh_(cc));
        const int m = lg * 4 + r;
        const int gidx = (w * 64 + m * 4 + 2 * j + (ln >> 3)) ^ (m >> 2);
        hbuf[p ^ 1][gidx * 8 + (ln & 7)] = hv;
        hreg[((size_t)(b0 + m) * SS + t) * HH + hb + 16 * j + ln] = hv;
      }
    __syncthreads();
  }
  #pragma unroll
  for (int j = 0; j < 2; ++j)
    #pragma unroll
    for (int r = 0; r < 4; ++r)
      cws[(size_t)(b0 + lg * 4 + r) * HH + hb + 16 * j + ln] = c[j][r];
}

// ---------------------------------------------------------------------------
// Tiled GEMM 128x128, K=256, 8 waves, XOR-swizzled LDS.
// OUT_BF16==1: xg slice -> bf16 gate-interleaved layout [(n&255)*4 + n>>8].
// OUT_BF16==0: proj -> fp32 [row*VV + n].
// ---------------------------------------------------------------------------
template <int OUT_BF16>
__global__ __launch_bounds__(512)
void gemm_kernel(const bf16* __restrict__ A, const float* __restrict__ W,
                 const float* __restrict__ bias0, const float* __restrict__ bias1,
                 void* __restrict__ out, int t0, int NCOL) {
  __shared__ bf16x8 alds[4096];   // 128 rows x 32 granules(16B)
  __shared__ bf16x8 blds[4096];
  const int tid = threadIdx.x, w = tid >> 6, l = tid & 63, lg = l >> 4, ln = l & 15;
  const int wm = w & 1, wn = w >> 1;
  const int R0 = blockIdx.x * 128, N0 = blockIdx.y * 128;
  {
    const int row = tid >> 2, seg = tid & 3;   // 4 thr/row, 64 cols each
    const bf16* asrc;
    if (OUT_BF16) {
      const int R = R0 + row;
      asrc = A + ((size_t)(R >> 6) * SS + t0 + (R & 63)) * HH + seg * 64;
    } else {
      asrc = A + ((size_t)R0 + row) * HH + seg * 64;
    }
    #pragma unroll
    for (int k = 0; k < 8; ++k) {
      const int g = seg * 8 + k;
      alds[row * 32 + (g ^ (row & 7))] = *(const bf16x8*)(asrc + k * 8);
    }
    const float* bsrc = W + (size_t)(N0 + row) * HH + seg * 64;
    #pragma unroll
    for (int k = 0; k < 8; ++k) {
      const int g = seg * 8 + k;
      blds[row * 32 + (g ^ (row & 7))] = cvt8(bsrc + k * 8);
    }
  }
  __syncthreads();
  f32x4 acc[4][2] = {};
  #pragma unroll
  for (int kc = 0; kc < 8; ++kc) {
    bf16x8 bfr[2];
    #pragma unroll
    for (int nt = 0; nt < 2; ++nt) {
      const int row = wn * 32 + nt * 16 + ln;
      bfr[nt] = blds[row * 32 + ((kc * 4 + lg) ^ (row & 7))];
    }
    #pragma unroll
    for (int mt = 0; mt < 4; ++mt) {
      const int row = wm * 64 + mt * 16 + ln;
      bf16x8 a = alds[row * 32 + ((kc * 4 + lg) ^ (row & 7))];
      #pragma unroll
      for (int nt = 0; nt < 2; ++nt)
        acc[mt][nt] = __builtin_amdgcn_mfma_f32_16x16x32_bf16(a, bfr[nt], acc[mt][nt], 0, 0, 0);
    }
  }
  #pragma unroll
  for (int nt = 0; nt < 2; ++nt) {
    const int n = N0 + wn * 32 + nt * 16 + ln;
    const float bv = bias0[n] + (bias1 ? bias1[n] : 0.f);
    const int col = OUT_BF16 ? ((n & 255) * 4 + (n >> 8)) : n;
    #pragma unroll
    for (int mt = 0; mt < 4; ++mt)
      #pragma unroll
      for (int r = 0; r < 4; ++r) {
        const size_t row = (size_t)R0 + wm * 64 + mt * 16 + lg * 4 + r;
        if (OUT_BF16) ((bf16*)out)[row * NCOL + col] = (bf16)(acc[mt][nt][r] + bv);
        else          ((float*)out)[row * NCOL + col] = acc[mt][nt][r] + bv;
      }
  }
}

extern "C" void kernel_launch(void* const* d_in, const int* in_sizes, int n_in,
                              void* d_out, int out_size, void* d_ws, size_t ws_size,
                              hipStream_t stream) {
  const int*   x   = (const int*)d_in[0];
  const float* emb = (const float*)d_in[1];
  const float* Wi0 = (const float*)d_in[2];
  const float* bi0 = (const float*)d_in[3];
  const float* Wh0 = (const float*)d_in[4];
  const float* bh0 = (const float*)d_in[5];
  const float* Wi1 = (const float*)d_in[6];
  const float* bi1 = (const float*)d_in[7];
  const float* Wh1 = (const float*)d_in[8];
  const float* bh1 = (const float*)d_in[9];
  const float* Wg  = (const float*)d_in[10];
  const float* bg  = (const float*)d_in[11];

  // ws: [flag 256B][table bf16 256KB][hreg bf16 128MB]  (< R4's proven need)
  char* ws = (char*)d_ws;
  int* flag = (int*)ws;
  unsigned short* table = (unsigned short*)(ws + 256);
  bf16* hreg = (bf16*)(ws + 256 + (size_t)VV * G4H * sizeof(unsigned short));
  const size_t need = 256 + (size_t)VV * G4H * sizeof(unsigned short)
                    + (size_t)BB * SS * HH * sizeof(bf16);
  if (ws_size < need) return;

  // d_out as scratch until proj: [xg slice 67.1MB][cws 512KB]
  unsigned short* xg = (unsigned short*)d_out;
  float* cws = (float*)((char*)d_out + (size_t)BB * TSL * G4H * sizeof(bf16));

  (void)hipMemsetAsync(flag, 0, sizeof(int), stream);
  detect_kernel<<<dim3(8), dim3(256), 0, stream>>>(x, flag);
  table_kernel<<<dim3(4, 128), dim3(256), 0, stream>>>(emb, Wi0, bi0, bh0, table);
  rec0_kernel<<<dim3(BB / 16), dim3(512), 0, stream>>>(x, flag, Wh0, table, hreg);
  for (int s = 0; s < NSEG; ++s) {
    const int t0 = s * TSL;
    gemm_kernel<1><<<dim3(BB * TSL / 128, G4H / 128), dim3(512), 0, stream>>>(
        hreg, Wi1, bi1, bh1, xg, t0, G4H);
    rec1_kernel<<<dim3(BB / 16), dim3(512), 0, stream>>>(xg, Wh1, hreg, cws, t0);
  }
  gemm_kernel<0><<<dim3(BB * SS / 128, VV / 128), dim3(512), 0, stream>>>(
      hreg, Wg, bg, nullptr, d_out, 0, VV);
}

// Round 9
// 5208.981 us; speedup vs baseline: 1.1607x; 1.0332x over previous
//
#include <hip/hip_runtime.h>
#include <hip/hip_bf16.h>

#define BB 512
#define SS 512
#define EE 128
#define HH 256
#define VV 128
#define G4H 1024
#define TSL 64              // rec1 time-slice length
#define NSEG (SS / TSL)     // 8

using bf16 = __bf16;
typedef __attribute__((ext_vector_type(8))) __bf16 bf16x8;
typedef __attribute__((ext_vector_type(4))) float f32x4;

__device__ __forceinline__ float rcpf(float x) { return __builtin_amdgcn_rcpf(x); }
__device__ __forceinline__ float exp2f_(float x) { return __builtin_amdgcn_exp2f(x); }
__device__ __forceinline__ float sigf(float x) {
  return rcpf(1.0f + exp2f_(-1.442695041f * x));
}
__device__ __forceinline__ float tanh_(float x) {
  return 2.0f * rcpf(1.0f + exp2f_(-2.885390082f * x)) - 1.0f;
}
__device__ __forceinline__ bf16x8 cvt8(const float* __restrict__ s) {
  bf16x8 f;
  #pragma unroll
  for (int j = 0; j < 8; ++j) f[j] = (bf16)s[j];
  return f;
}
__device__ __forceinline__ float bf2f(unsigned short u) {
  return __uint_as_float(((unsigned)u) << 16);
}

// ---------------------------------------------------------------------------
// x dtype sniffer (validated R4): odd 32-bit words all zero <=> int64.
// ---------------------------------------------------------------------------
__global__ void detect_kernel(const int* __restrict__ x, int* __restrict__ flag) {
  const int i = blockIdx.x * 256 + threadIdx.x;
  if (x[2 * i + 1] != 0) atomicOr(flag, 1);
}

// ---------------------------------------------------------------------------
// Gate-interleaved bf16 table: table[v][u*4+q] = emb[v,:].Wi0[q*256+u,:] + biases
// ---------------------------------------------------------------------------
__global__ __launch_bounds__(256)
void table_kernel(const float* __restrict__ emb, const float* __restrict__ Wi,
                  const float* __restrict__ bi, const float* __restrict__ bh,
                  unsigned short* __restrict__ table) {
  const int g = blockIdx.x * 256 + threadIdx.x;  // 0..1023
  const int v = blockIdx.y;                      // 0..127
  float s = bi[g] + bh[g];
  const float* er = emb + v * EE;
  const float* wr = Wi + (size_t)g * EE;
  #pragma unroll 4
  for (int e = 0; e < EE; ++e) s += er[e] * wr[e];
  const bf16 b = (bf16)s;
  table[v * G4H + (g & 255) * 4 + (g >> 8)] = *(const unsigned short*)&b;
}

// ---------------------------------------------------------------------------
// MFMA recurrence layer 0. 32 WGs x 512 thr (8 waves, PINNED 2 waves/EU ->
// 256-VGPR budget). Wave owns hidden cols [32w,32w+32) = 8 MFMA tiles:
//   VGPR-resident: f(j0,j1), i(j0,j1), g(j0)      -> Wf[5][8], 160 regs
//   LDS-resident : o(j0,j1)                        -> wlds, 128 KB
//   L2-streamed  : g(j1)                           -> 8 x bf16x8 loads/step
// h state fragment-major in LDS (XOR-swizzled, verified consistent R8).
// Register budget ~243 < 256 so Wf is NOT demoted (readout: VGPR_Count).
// ---------------------------------------------------------------------------
__global__ __launch_bounds__(512) __attribute__((amdgpu_waves_per_eu(2, 2)))
void rec0_kernel(const int* __restrict__ x, const int* __restrict__ flagp,
                 const float* __restrict__ Wh,
                 const unsigned short* __restrict__ table,
                 bf16* __restrict__ h1) {
  __shared__ bf16 hbuf[2][4096];
  __shared__ bf16x8 wlds[8192];      // 128KB o-gate weights
  const int tid = threadIdx.x, w = tid >> 6, l = tid & 63, lg = l >> 4, ln = l & 15;
  const int b0 = blockIdx.x * 16, hb = w * 32;
  const int is32 = *flagp;

  // resident weights: qj -> (gate q, col-half j): 0..3 => (qj>>1, qj&1); 4 => (2,0)
  bf16x8 Wf[5][8];
  #pragma unroll
  for (int qj = 0; qj < 5; ++qj) {
    const int q = (qj < 4) ? (qj >> 1) : 2;
    const int j = (qj < 4) ? (qj & 1) : 0;
    const int n = q * HH + hb + 16 * j + ln;
    #pragma unroll
    for (int kc = 0; kc < 8; ++kc) Wf[qj][kc] = cvt8(Wh + (size_t)n * HH + kc * 32 + lg * 8);
  }
  #pragma unroll
  for (int j = 0; j < 2; ++j) {                  // o-gate -> LDS
    const int n = 3 * HH + hb + 16 * j + ln;
    #pragma unroll
    for (int kc = 0; kc < 8; ++kc)
      wlds[((w * 2 + j) * 8 + kc) * 64 + ln * 4 + lg] = cvt8(Wh + (size_t)n * HH + kc * 32 + lg * 8);
  }
  // streamed tile base: gate g (q=2), j=1
  const float* gsrc = Wh + (size_t)(2 * HH + hb + 16 + ln) * HH + lg * 8;

  { bf16x8 z = {}; ((bf16x8*)hbuf[0])[tid] = z; }
  float c[2][4] = {};

  // 32-bit h1 store offsets (region < 2^27 elems) per (r, j)
  int hoff[4];
  #pragma unroll
  for (int r = 0; r < 4; ++r)
    hoff[r] = ((b0 + lg * 4 + r) * SS) * HH + hb + ln;

  int idx[4];
  #pragma unroll
  for (int r = 0; r < 4; ++r) {
    const long xi = (long)(b0 + lg * 4 + r) * SS;
    idx[r] = x[is32 ? xi : 2 * xi] & 127;
  }
  __syncthreads();

  #pragma unroll 1
  for (int t = 0; t < SS; ++t) {
    const int p = t & 1;
    // table gather for step t (consumed in epilogue)
    ushort4 tj[4][2];
    #pragma unroll
    for (int r = 0; r < 4; ++r) {
      const unsigned short* base = table + (size_t)idx[r] * G4H + (hb + ln) * 4;
      tj[r][0] = *(const ushort4*)base;
      tj[r][1] = *(const ushort4*)(base + 64);
    }
    // prefetch x for t+1
    if (t + 1 < SS) {
      #pragma unroll
      for (int r = 0; r < 4; ++r) {
        const long xi = (long)(b0 + lg * 4 + r) * SS + (t + 1);
        idx[r] = x[is32 ? xi : 2 * xi] & 127;
      }
    }
    f32x4 acc[4][2] = {};
    #pragma unroll
    for (int kc = 0; kc < 8; ++kc) {
      bf16x8 a = ((const bf16x8*)hbuf[p])[(kc * 64 + ln * 4 + lg) ^ (ln >> 2)];
      acc[0][0] = __builtin_amdgcn_mfma_f32_16x16x32_bf16(a, Wf[0][kc], acc[0][0], 0, 0, 0);
      acc[0][1] = __builtin_amdgcn_mfma_f32_16x16x32_bf16(a, Wf[1][kc], acc[0][1], 0, 0, 0);
      acc[1][0] = __builtin_amdgcn_mfma_f32_16x16x32_bf16(a, Wf[2][kc], acc[1][0], 0, 0, 0);
      acc[1][1] = __builtin_amdgcn_mfma_f32_16x16x32_bf16(a, Wf[3][kc], acc[1][1], 0, 0, 0);
      acc[2][0] = __builtin_amdgcn_mfma_f32_16x16x32_bf16(a, Wf[4][kc], acc[2][0], 0, 0, 0);
      {
        bf16x8 gw = cvt8(gsrc + kc * 32);                       // streamed g(j1)
        acc[2][1] = __builtin_amdgcn_mfma_f32_16x16x32_bf16(a, gw, acc[2][1], 0, 0, 0);
      }
      #pragma unroll
      for (int j = 0; j < 2; ++j) {
        bf16x8 bw = wlds[((w * 2 + j) * 8 + kc) * 64 + ln * 4 + lg];
        acc[3][j] = __builtin_amdgcn_mfma_f32_16x16x32_bf16(a, bw, acc[3][j], 0, 0, 0);
      }
    }
    // epilogue: add table contribution, nonlinearity, state update
    #pragma unroll
    for (int j = 0; j < 2; ++j)
      #pragma unroll
      for (int r = 0; r < 4; ++r) {
        const float fg = sigf(acc[0][j][r] + bf2f(tj[r][j].x));
        const float ig = sigf(acc[1][j][r] + bf2f(tj[r][j].y));
        const float gg = tanh_(acc[2][j][r] + bf2f(tj[r][j].z));
        const float og = sigf(acc[3][j][r] + bf2f(tj[r][j].w));
        const float cc = fg * c[j][r] + ig * gg;
        c[j][r] = cc;
        const bf16 hv = (bf16)(og * tanh_(cc));
        const int m = lg * 4 + r;
        const int gidx = (w * 64 + m * 4 + 2 * j + (ln >> 3)) ^ (m >> 2);
        hbuf[p ^ 1][gidx * 8 + (ln & 7)] = hv;
        h1[hoff[r] + t * HH + 16 * j] = hv;
      }
    __syncthreads();
  }
}

// ---------------------------------------------------------------------------
// MFMA recurrence layer 1, one time-slice [t0,t0+TSL). Same residency plan;
// gate init gathered from gate-interleaved bf16 xg (includes bi1+bh1).
// ---------------------------------------------------------------------------
__global__ __launch_bounds__(512) __attribute__((amdgpu_waves_per_eu(2, 2)))
void rec1_kernel(const unsigned short* __restrict__ xg, const float* __restrict__ Wh,
                 bf16* __restrict__ hreg, float* __restrict__ cws, int t0) {
  __shared__ bf16 hbuf[2][4096];
  __shared__ bf16x8 wlds[8192];
  const int tid = threadIdx.x, w = tid >> 6, l = tid & 63, lg = l >> 4, ln = l & 15;
  const int b0 = blockIdx.x * 16, hb = w * 32;

  bf16x8 Wf[5][8];
  #pragma unroll
  for (int qj = 0; qj < 5; ++qj) {
    const int q = (qj < 4) ? (qj >> 1) : 2;
    const int j = (qj < 4) ? (qj & 1) : 0;
    const int n = q * HH + hb + 16 * j + ln;
    #pragma unroll
    for (int kc = 0; kc < 8; ++kc) Wf[qj][kc] = cvt8(Wh + (size_t)n * HH + kc * 32 + lg * 8);
  }
  #pragma unroll
  for (int j = 0; j < 2; ++j) {
    const int n = 3 * HH + hb + 16 * j + ln;
    #pragma unroll
    for (int kc = 0; kc < 8; ++kc)
      wlds[((w * 2 + j) * 8 + kc) * 64 + ln * 4 + lg] = cvt8(Wh + (size_t)n * HH + kc * 32 + lg * 8);
  }
  const float* gsrc = Wh + (size_t)(2 * HH + hb + 16 + ln) * HH + lg * 8;

  int hoff[4];
  #pragma unroll
  for (int r = 0; r < 4; ++r)
    hoff[r] = ((b0 + lg * 4 + r) * SS) * HH + hb + ln;

  float c[2][4];
  if (t0 == 0) {
    #pragma unroll
    for (int j = 0; j < 2; ++j)
      #pragma unroll
      for (int r = 0; r < 4; ++r) c[j][r] = 0.f;
    bf16x8 z = {};
    ((bf16x8*)hbuf[0])[tid] = z;
  } else {
    #pragma unroll
    for (int j = 0; j < 2; ++j)
      #pragma unroll
      for (int r = 0; r < 4; ++r) {
        const int m = lg * 4 + r, col = hb + 16 * j + ln;
        c[j][r] = cws[(size_t)(b0 + m) * HH + col];
        const bf16 hv = hreg[((size_t)(b0 + m) * SS + (t0 - 1)) * HH + col];
        const int gidx = (w * 64 + m * 4 + 2 * j + (ln >> 3)) ^ (m >> 2);
        hbuf[0][gidx * 8 + (ln & 7)] = hv;
      }
  }
  __syncthreads();

  #pragma unroll 1
  for (int tt = 0; tt < TSL; ++tt) {
    const int t = t0 + tt, p = tt & 1;
    ushort4 tj[4][2];
    #pragma unroll
    for (int r = 0; r < 4; ++r) {
      const unsigned short* base =
          xg + ((size_t)(b0 + lg * 4 + r) * TSL + tt) * G4H + (hb + ln) * 4;
      tj[r][0] = *(const ushort4*)base;
      tj[r][1] = *(const ushort4*)(base + 64);
    }
    f32x4 acc[4][2] = {};
    #pragma unroll
    for (int kc = 0; kc < 8; ++kc) {
      bf16x8 a = ((const bf16x8*)hbuf[p])[(kc * 64 + ln * 4 + lg) ^ (ln >> 2)];
      acc[0][0] = __builtin_amdgcn_mfma_f32_16x16x32_bf16(a, Wf[0][kc], acc[0][0], 0, 0, 0);
      acc[0][1] = __builtin_amdgcn_mfma_f32_16x16x32_bf16(a, Wf[1][kc], acc[0][1], 0, 0, 0);
      acc[1][0] = __builtin_amdgcn_mfma_f32_16x16x32_bf16(a, Wf[2][kc], acc[1][0], 0, 0, 0);
      acc[1][1] = __builtin_amdgcn_mfma_f32_16x16x32_bf16(a, Wf[3][kc], acc[1][1], 0, 0, 0);
      acc[2][0] = __builtin_amdgcn_mfma_f32_16x16x32_bf16(a, Wf[4][kc], acc[2][0], 0, 0, 0);
      {
        bf16x8 gw = cvt8(gsrc + kc * 32);
        acc[2][1] = __builtin_amdgcn_mfma_f32_16x16x32_bf16(a, gw, acc[2][1], 0, 0, 0);
      }
      #pragma unroll
      for (int j = 0; j < 2; ++j) {
        bf16x8 bw = wlds[((w * 2 + j) * 8 + kc) * 64 + ln * 4 + lg];
        acc[3][j] = __builtin_amdgcn_mfma_f32_16x16x32_bf16(a, bw, acc[3][j], 0, 0, 0);
      }
    }
    #pragma unroll
    for (int j = 0; j < 2; ++j)
      #pragma unroll
      for (int r = 0; r < 4; ++r) {
        const float fg = sigf(acc[0][j][r] + bf2f(tj[r][j].x));
        const float ig = sigf(acc[1][j][r] + bf2f(tj[r][j].y));
        const float gg = tanh_(acc[2][j][r] + bf2f(tj[r][j].z));
        const float og = sigf(acc[3][j][r] + bf2f(tj[r][j].w));
        const float cc = fg * c[j][r] + ig * gg;
        c[j][r] = cc;
        const bf16 hv = (bf16)(og * tanh_(cc));
        const int m = lg * 4 + r;
        const int gidx = (w * 64 + m * 4 + 2 * j + (ln >> 3)) ^ (m >> 2);
        hbuf[p ^ 1][gidx * 8 + (ln & 7)] = hv;
        hreg[hoff[r] + t * HH + 16 * j] = hv;
      }
    __syncthreads();
  }
  #pragma unroll
  for (int j = 0; j < 2; ++j)
    #pragma unroll
    for (int r = 0; r < 4; ++r)
      cws[(size_t)(b0 + lg * 4 + r) * HH + hb + 16 * j + ln] = c[j][r];
}

// ---------------------------------------------------------------------------
// Tiled GEMM 128x128, K=256, 8 waves, XOR-swizzled LDS.
// OUT_BF16==1: xg slice -> bf16 gate-interleaved layout [(n&255)*4 + n>>8].
// OUT_BF16==0: proj -> fp32 [row*VV + n].
// ---------------------------------------------------------------------------
template <int OUT_BF16>
__global__ __launch_bounds__(512)
void gemm_kernel(const bf16* __restrict__ A, const float* __restrict__ W,
                 const float* __restrict__ bias0, const float* __restrict__ bias1,
                 void* __restrict__ out, int t0, int NCOL) {
  __shared__ bf16x8 alds[4096];   // 128 rows x 32 granules(16B)
  __shared__ bf16x8 blds[4096];
  const int tid = threadIdx.x, w = tid >> 6, l = tid & 63, lg = l >> 4, ln = l & 15;
  const int wm = w & 1, wn = w >> 1;
  const int R0 = blockIdx.x * 128, N0 = blockIdx.y * 128;
  {
    const int row = tid >> 2, seg = tid & 3;   // 4 thr/row, 64 cols each
    const bf16* asrc;
    if (OUT_BF16) {
      const int R = R0 + row;
      asrc = A + ((size_t)(R >> 6) * SS + t0 + (R & 63)) * HH + seg * 64;
    } else {
      asrc = A + ((size_t)R0 + row) * HH + seg * 64;
    }
    #pragma unroll
    for (int k = 0; k < 8; ++k) {
      const int g = seg * 8 + k;
      alds[row * 32 + (g ^ (row & 7))] = *(const bf16x8*)(asrc + k * 8);
    }
    const float* bsrc = W + (size_t)(N0 + row) * HH + seg * 64;
    #pragma unroll
    for (int k = 0; k < 8; ++k) {
      const int g = seg * 8 + k;
      blds[row * 32 + (g ^ (row & 7))] = cvt8(bsrc + k * 8);
    }
  }
  __syncthreads();
  f32x4 acc[4][2] = {};
  #pragma unroll
  for (int kc = 0; kc < 8; ++kc) {
    bf16x8 bfr[2];
    #pragma unroll
    for (int nt = 0; nt < 2; ++nt) {
      const int row = wn * 32 + nt * 16 + ln;
      bfr[nt] = blds[row * 32 + ((kc * 4 + lg) ^ (row & 7))];
    }
    #pragma unroll
    for (int mt = 0; mt < 4; ++mt) {
      const int row = wm * 64 + mt * 16 + ln;
      bf16x8 a = alds[row * 32 + ((kc * 4 + lg) ^ (row & 7))];
      #pragma unroll
      for (int nt = 0; nt < 2; ++nt)
        acc[mt][nt] = __builtin_amdgcn_mfma_f32_16x16x32_bf16(a, bfr[nt], acc[mt][nt], 0, 0, 0);
    }
  }
  #pragma unroll
  for (int nt = 0; nt < 2; ++nt) {
    const int n = N0 + wn * 32 + nt * 16 + ln;
    const float bv = bias0[n] + (bias1 ? bias1[n] : 0.f);
    const int col = OUT_BF16 ? ((n & 255) * 4 + (n >> 8)) : n;
    #pragma unroll
    for (int mt = 0; mt < 4; ++mt)
      #pragma unroll
      for (int r = 0; r < 4; ++r) {
        const size_t row = (size_t)R0 + wm * 64 + mt * 16 + lg * 4 + r;
        if (OUT_BF16) ((bf16*)out)[row * NCOL + col] = (bf16)(acc[mt][nt][r] + bv);
        else          ((float*)out)[row * NCOL + col] = acc[mt][nt][r] + bv;
      }
  }
}

extern "C" void kernel_launch(void* const* d_in, const int* in_sizes, int n_in,
                              void* d_out, int out_size, void* d_ws, size_t ws_size,
                              hipStream_t stream) {
  const int*   x   = (const int*)d_in[0];
  const float* emb = (const float*)d_in[1];
  const float* Wi0 = (const float*)d_in[2];
  const float* bi0 = (const float*)d_in[3];
  const float* Wh0 = (const float*)d_in[4];
  const float* bh0 = (const float*)d_in[5];
  const float* Wi1 = (const float*)d_in[6];
  const float* bi1 = (const float*)d_in[7];
  const float* Wh1 = (const float*)d_in[8];
  const float* bh1 = (const float*)d_in[9];
  const float* Wg  = (const float*)d_in[10];
  const float* bg  = (const float*)d_in[11];

  // ws: [flag 256B][table bf16 256KB][hreg bf16 128MB]
  char* ws = (char*)d_ws;
  int* flag = (int*)ws;
  unsigned short* table = (unsigned short*)(ws + 256);
  bf16* hreg = (bf16*)(ws + 256 + (size_t)VV * G4H * sizeof(unsigned short));
  const size_t need = 256 + (size_t)VV * G4H * sizeof(unsigned short)
                    + (size_t)BB * SS * HH * sizeof(bf16);
  if (ws_size < need) return;

  // d_out as scratch until proj: [xg slice 67.1MB][cws 512KB]
  unsigned short* xg = (unsigned short*)d_out;
  float* cws = (float*)((char*)d_out + (size_t)BB * TSL * G4H * sizeof(bf16));

  (void)hipMemsetAsync(flag, 0, sizeof(int), stream);
  detect_kernel<<<dim3(8), dim3(256), 0, stream>>>(x, flag);
  table_kernel<<<dim3(4, 128), dim3(256), 0, stream>>>(emb, Wi0, bi0, bh0, table);
  rec0_kernel<<<dim3(BB / 16), dim3(512), 0, stream>>>(x, flag, Wh0, table, hreg);
  for (int s = 0; s < NSEG; ++s) {
    const int t0 = s * TSL;
    gemm_kernel<1><<<dim3(BB * TSL / 128, G4H / 128), dim3(512), 0, stream>>>(
        hreg, Wi1, bi1, bh1, xg, t0, G4H);
    rec1_kernel<<<dim3(BB / 16), dim3(512), 0, stream>>>(xg, Wh1, hreg, cws, t0);
  }
  gemm_kernel<0><<<dim3(BB * SS / 128, VV / 128), dim3(512), 0, stream>>>(
      hreg, Wg, bg, nullptr, d_out, 0, VV);
}

// Round 11
// 4450.190 us; speedup vs baseline: 1.3587x; 1.1705x over previous
//
#include <hip/hip_runtime.h>
#include <hip/hip_bf16.h>

#define BB 512
#define SS 512
#define EE 128
#define HH 256
#define VV 128
#define G4H 1024
#define TSL 64              // rec1 time-slice length
#define NSEG (SS / TSL)     // 8

using bf16 = __bf16;
typedef __attribute__((ext_vector_type(8))) __bf16 bf16x8;
typedef __attribute__((ext_vector_type(4))) float f32x4;
typedef __attribute__((ext_vector_type(4))) unsigned int u32x4;

__device__ __forceinline__ float rcpf(float x) { return __builtin_amdgcn_rcpf(x); }
__device__ __forceinline__ float exp2f_(float x) { return __builtin_amdgcn_exp2f(x); }
__device__ __forceinline__ float sigf(float x) {
  return rcpf(1.0f + exp2f_(-1.442695041f * x));
}
__device__ __forceinline__ float tanh_(float x) {
  return 2.0f * rcpf(1.0f + exp2f_(-2.885390082f * x)) - 1.0f;
}
__device__ __forceinline__ bf16x8 cvt8(const float* __restrict__ s) {
  bf16x8 f;
  #pragma unroll
  for (int j = 0; j < 8; ++j) f[j] = (bf16)s[j];
  return f;
}
__device__ __forceinline__ float bf2f(unsigned short u) {
  return __uint_as_float(((unsigned)u) << 16);
}

// ---------------------------------------------------------------------------
// x dtype sniffer (validated R4): odd 32-bit words all zero <=> int64.
// ---------------------------------------------------------------------------
__global__ void detect_kernel(const int* __restrict__ x, int* __restrict__ flag) {
  const int i = blockIdx.x * 256 + threadIdx.x;
  if (x[2 * i + 1] != 0) atomicOr(flag, 1);
}

// ---------------------------------------------------------------------------
// Gate-interleaved bf16 table: table[v][u*4+q] = emb[v,:].Wi0[q*256+u,:] + biases
// ---------------------------------------------------------------------------
__global__ __launch_bounds__(256)
void table_kernel(const float* __restrict__ emb, const float* __restrict__ Wi,
                  const float* __restrict__ bi, const float* __restrict__ bh,
                  unsigned short* __restrict__ table) {
  const int g = blockIdx.x * 256 + threadIdx.x;  // 0..1023
  const int v = blockIdx.y;                      // 0..127
  float s = bi[g] + bh[g];
  const float* er = emb + v * EE;
  const float* wr = Wi + (size_t)g * EE;
  #pragma unroll 4
  for (int e = 0; e < EE; ++e) s += er[e] * wr[e];
  const bf16 b = (bf16)s;
  table[v * G4H + (g & 255) * 4 + (g >> 8)] = *(const unsigned short*)&b;
}

// ---------------------------------------------------------------------------
// Weight prep: Wh (fp32 [1024][256]) -> bf16 MFMA-fragment granules.
// Flat granule index = w*4096 + s*512 + kc*64 + l  (16B each, 512KB/layer).
// Slot s -> (gate q = s>>1, col-half j = s&1); lane l=(lg,ln):
//   granule holds Wh[q*256 + w*32 + 16j + ln][kc*32 + lg*8 .. +8).
// ---------------------------------------------------------------------------
__global__ __launch_bounds__(256)
void wprep_kernel(const float* __restrict__ Wh0, const float* __restrict__ Wh1,
                  bf16x8* __restrict__ wb0, bf16x8* __restrict__ wb1) {
  const int idx = blockIdx.x * 256 + threadIdx.x;   // 0..32767
  const int l = idx & 63, kc = (idx >> 6) & 7, s = (idx >> 9) & 7, w = idx >> 12;
  const int lg = l >> 4, ln = l & 15;
  const int n = (s >> 1) * HH + w * 32 + 16 * (s & 1) + ln;
  const int k0 = kc * 32 + lg * 8;
  const float* src = (blockIdx.y ? Wh1 : Wh0) + (size_t)n * HH + k0;
  (blockIdx.y ? wb1 : wb0)[idx] = cvt8(src);
}

// ---------------------------------------------------------------------------
// MFMA recurrence layer 0. 32 WGs x 512 thr (8 waves, 2/SIMD). Per wave
// (32 hidden cols x 4 gates = 8 tiles):
//   VGPR-pinned  : slots 0-3 (f j0/j1, i j0/j1) -- 128 regs, pinned via
//                  empty asm "+v" (non-rematerializable opaque defs).
//   L2-streamed  : slots 4,5 (g j0/j1) -- 2 x 16B bf16 loads per kc.
//   LDS-resident : slots 6,7 (o j0/j1) -- 128 KB.
// h state LDS layout = R5's verified linear fragment-major.
// ---------------------------------------------------------------------------
__global__ __launch_bounds__(512) __attribute__((amdgpu_waves_per_eu(2)))
void rec0_kernel(const int* __restrict__ x, const int* __restrict__ flagp,
                 const bf16x8* __restrict__ wb,
                 const unsigned short* __restrict__ table,
                 bf16* __restrict__ h1) {
  __shared__ bf16 hbuf[2][4096];
  __shared__ bf16x8 wlds[8192];      // 128KB o-gate weights
  const int tid = threadIdx.x, w = tid >> 6, l = tid & 63, lg = l >> 4, ln = l & 15;
  const int b0 = blockIdx.x * 16, hb = w * 32;
  const int is32 = *flagp;
  const u32x4* __restrict__ wbu = (const u32x4*)wb;

  // VGPR-resident weight slots 0..3
  u32x4 Wa[4][8];
  #pragma unroll
  for (int s = 0; s < 4; ++s)
    #pragma unroll
    for (int kc = 0; kc < 8; ++kc)
      Wa[s][kc] = wbu[w * 4096 + s * 512 + kc * 64 + l];
  // o-gate slots 6,7 -> LDS
  #pragma unroll
  for (int j = 0; j < 2; ++j)
    #pragma unroll
    for (int kc = 0; kc < 8; ++kc)
      wlds[((w * 2 + j) * 8 + kc) * 64 + l] = wb[w * 4096 + (6 + j) * 512 + kc * 64 + l];
  // pin: defs become opaque asm outputs (VGPR class) -> no remat possible
  #pragma unroll
  for (int s = 0; s < 4; ++s)
    #pragma unroll
    for (int kc = 0; kc < 8; ++kc)
      asm volatile("" : "+v"(Wa[s][kc]));
  // streamed g-gate slot bases (bf16 granules, 16B/lane, loop-invariant addr)
  const bf16x8* __restrict__ gsrc0 = wb + w * 4096 + 4 * 512 + l;
  const bf16x8* __restrict__ gsrc1 = wb + w * 4096 + 5 * 512 + l;

  { bf16x8 z = {}; ((bf16x8*)hbuf[0])[tid] = z; }
  float c[2][4] = {};

  int hoff[4];
  #pragma unroll
  for (int r = 0; r < 4; ++r)
    hoff[r] = ((b0 + lg * 4 + r) * SS) * HH + hb + ln;

  int idx[4];
  #pragma unroll
  for (int r = 0; r < 4; ++r) {
    const long xi = (long)(b0 + lg * 4 + r) * SS;
    idx[r] = x[is32 ? xi : 2 * xi] & 127;
  }
  __syncthreads();

  #pragma unroll 1
  for (int t = 0; t < SS; ++t) {
    const int p = t & 1;
    // table gather for step t (consumed in epilogue; hides under MFMA loop)
    ushort4 tj[4][2];
    #pragma unroll
    for (int r = 0; r < 4; ++r) {
      const unsigned short* base = table + (size_t)idx[r] * G4H + (hb + ln) * 4;
      tj[r][0] = *(const ushort4*)base;
      tj[r][1] = *(const ushort4*)(base + 64);
    }
    if (t + 1 < SS) {
      #pragma unroll
      for (int r = 0; r < 4; ++r) {
        const long xi = (long)(b0 + lg * 4 + r) * SS + (t + 1);
        idx[r] = x[is32 ? xi : 2 * xi] & 127;
      }
    }
    f32x4 acc[4][2] = {};
    #pragma unroll
    for (int kc = 0; kc < 8; ++kc) {
      bf16x8 a = ((const bf16x8*)hbuf[p])[kc * 64 + ln * 4 + lg];
      acc[0][0] = __builtin_amdgcn_mfma_f32_16x16x32_bf16(a, __builtin_bit_cast(bf16x8, Wa[0][kc]), acc[0][0], 0, 0, 0);
      acc[0][1] = __builtin_amdgcn_mfma_f32_16x16x32_bf16(a, __builtin_bit_cast(bf16x8, Wa[1][kc]), acc[0][1], 0, 0, 0);
      acc[1][0] = __builtin_amdgcn_mfma_f32_16x16x32_bf16(a, __builtin_bit_cast(bf16x8, Wa[2][kc]), acc[1][0], 0, 0, 0);
      acc[1][1] = __builtin_amdgcn_mfma_f32_16x16x32_bf16(a, __builtin_bit_cast(bf16x8, Wa[3][kc]), acc[1][1], 0, 0, 0);
      acc[2][0] = __builtin_amdgcn_mfma_f32_16x16x32_bf16(a, gsrc0[kc * 64], acc[2][0], 0, 0, 0);
      acc[2][1] = __builtin_amdgcn_mfma_f32_16x16x32_bf16(a, gsrc1[kc * 64], acc[2][1], 0, 0, 0);
      #pragma unroll
      for (int j = 0; j < 2; ++j) {
        bf16x8 bw = wlds[((w * 2 + j) * 8 + kc) * 64 + l];
        acc[3][j] = __builtin_amdgcn_mfma_f32_16x16x32_bf16(a, bw, acc[3][j], 0, 0, 0);
      }
    }
    // epilogue: add table contribution, nonlinearity, state update
    #pragma unroll
    for (int j = 0; j < 2; ++j)
      #pragma unroll
      for (int r = 0; r < 4; ++r) {
        const float fg = sigf(acc[0][j][r] + bf2f(tj[r][j].x));
        const float ig = sigf(acc[1][j][r] + bf2f(tj[r][j].y));
        const float gg = tanh_(acc[2][j][r] + bf2f(tj[r][j].z));
        const float og = sigf(acc[3][j][r] + bf2f(tj[r][j].w));
        const float cc = fg * c[j][r] + ig * gg;
        c[j][r] = cc;
        const bf16 hv = (bf16)(og * tanh_(cc));
        const int m = lg * 4 + r;
        hbuf[p ^ 1][(w * 64 + m * 4 + 2 * j + (ln >> 3)) * 8 + (ln & 7)] = hv;
        h1[hoff[r] + t * HH + 16 * j] = hv;
      }
    __syncthreads();
  }
}

// ---------------------------------------------------------------------------
// MFMA recurrence layer 1, one time-slice [t0,t0+TSL). Same residency plan;
// gate init gathered from gate-interleaved bf16 xg (includes bi1+bh1).
// ---------------------------------------------------------------------------
__global__ __launch_bounds__(512) __attribute__((amdgpu_waves_per_eu(2)))
void rec1_kernel(const unsigned short* __restrict__ xg, const bf16x8* __restrict__ wb,
                 bf16* __restrict__ hreg, float* __restrict__ cws, int t0) {
  __shared__ bf16 hbuf[2][4096];
  __shared__ bf16x8 wlds[8192];
  const int tid = threadIdx.x, w = tid >> 6, l = tid & 63, lg = l >> 4, ln = l & 15;
  const int b0 = blockIdx.x * 16, hb = w * 32;
  const u32x4* __restrict__ wbu = (const u32x4*)wb;

  u32x4 Wa[4][8];
  #pragma unroll
  for (int s = 0; s < 4; ++s)
    #pragma unroll
    for (int kc = 0; kc < 8; ++kc)
      Wa[s][kc] = wbu[w * 4096 + s * 512 + kc * 64 + l];
  #pragma unroll
  for (int j = 0; j < 2; ++j)
    #pragma unroll
    for (int kc = 0; kc < 8; ++kc)
      wlds[((w * 2 + j) * 8 + kc) * 64 + l] = wb[w * 4096 + (6 + j) * 512 + kc * 64 + l];
  #pragma unroll
  for (int s = 0; s < 4; ++s)
    #pragma unroll
    for (int kc = 0; kc < 8; ++kc)
      asm volatile("" : "+v"(Wa[s][kc]));
  const bf16x8* __restrict__ gsrc0 = wb + w * 4096 + 4 * 512 + l;
  const bf16x8* __restrict__ gsrc1 = wb + w * 4096 + 5 * 512 + l;

  int hoff[4];
  #pragma unroll
  for (int r = 0; r < 4; ++r)
    hoff[r] = ((b0 + lg * 4 + r) * SS) * HH + hb + ln;

  float c[2][4];
  if (t0 == 0) {
    #pragma unroll
    for (int j = 0; j < 2; ++j)
      #pragma unroll
      for (int r = 0; r < 4; ++r) c[j][r] = 0.f;
    bf16x8 z = {};
    ((bf16x8*)hbuf[0])[tid] = z;
  } else {
    #pragma unroll
    for (int j = 0; j < 2; ++j)
      #pragma unroll
      for (int r = 0; r < 4; ++r) {
        const int m = lg * 4 + r, col = hb + 16 * j + ln;
        c[j][r] = cws[(size_t)(b0 + m) * HH + col];
        const bf16 hv = hreg[((size_t)(b0 + m) * SS + (t0 - 1)) * HH + col];
        hbuf[0][(w * 64 + m * 4 + 2 * j + (ln >> 3)) * 8 + (ln & 7)] = hv;
      }
  }
  __syncthreads();

  #pragma unroll 1
  for (int tt = 0; tt < TSL; ++tt) {
    const int t = t0 + tt, p = tt & 1;
    ushort4 tj[4][2];
    #pragma unroll
    for (int r = 0; r < 4; ++r) {
      const unsigned short* base =
          xg + ((size_t)(b0 + lg * 4 + r) * TSL + tt) * G4H + (hb + ln) * 4;
      tj[r][0] = *(const ushort4*)base;
      tj[r][1] = *(const ushort4*)(base + 64);
    }
    f32x4 acc[4][2] = {};
    #pragma unroll
    for (int kc = 0; kc < 8; ++kc) {
      bf16x8 a = ((const bf16x8*)hbuf[p])[kc * 64 + ln * 4 + lg];
      acc[0][0] = __builtin_amdgcn_mfma_f32_16x16x32_bf16(a, __builtin_bit_cast(bf16x8, Wa[0][kc]), acc[0][0], 0, 0, 0);
      acc[0][1] = __builtin_amdgcn_mfma_f32_16x16x32_bf16(a, __builtin_bit_cast(bf16x8, Wa[1][kc]), acc[0][1], 0, 0, 0);
      acc[1][0] = __builtin_amdgcn_mfma_f32_16x16x32_bf16(a, __builtin_bit_cast(bf16x8, Wa[2][kc]), acc[1][0], 0, 0, 0);
      acc[1][1] = __builtin_amdgcn_mfma_f32_16x16x32_bf16(a, __builtin_bit_cast(bf16x8, Wa[3][kc]), acc[1][1], 0, 0, 0);
      acc[2][0] = __builtin_amdgcn_mfma_f32_16x16x32_bf16(a, gsrc0[kc * 64], acc[2][0], 0, 0, 0);
      acc[2][1] = __builtin_amdgcn_mfma_f32_16x16x32_bf16(a, gsrc1[kc * 64], acc[2][1], 0, 0, 0);
      #pragma unroll
      for (int j = 0; j < 2; ++j) {
        bf16x8 bw = wlds[((w * 2 + j) * 8 + kc) * 64 + l];
        acc[3][j] = __builtin_amdgcn_mfma_f32_16x16x32_bf16(a, bw, acc[3][j], 0, 0, 0);
      }
    }
    #pragma unroll
    for (int j = 0; j < 2; ++j)
      #pragma unroll
      for (int r = 0; r < 4; ++r) {
        const float fg = sigf(acc[0][j][r] + bf2f(tj[r][j].x));
        const float ig = sigf(acc[1][j][r] + bf2f(tj[r][j].y));
        const float gg = tanh_(acc[2][j][r] + bf2f(tj[r][j].z));
        const float og = sigf(acc[3][j][r] + bf2f(tj[r][j].w));
        const float cc = fg * c[j][r] + ig * gg;
        c[j][r] = cc;
        const bf16 hv = (bf16)(og * tanh_(cc));
        const int m = lg * 4 + r;
        hbuf[p ^ 1][(w * 64 + m * 4 + 2 * j + (ln >> 3)) * 8 + (ln & 7)] = hv;
        hreg[hoff[r] + t * HH + 16 * j] = hv;
      }
    __syncthreads();
  }
  #pragma unroll
  for (int j = 0; j < 2; ++j)
    #pragma unroll
    for (int r = 0; r < 4; ++r)
      cws[(size_t)(b0 + lg * 4 + r) * HH + hb + 16 * j + ln] = c[j][r];
}

// ---------------------------------------------------------------------------
// Tiled GEMM 128x128, K=256, 8 waves, XOR-swizzled LDS.
// OUT_BF16==1: xg slice -> bf16 gate-interleaved layout [(n&255)*4 + n>>8].
// OUT_BF16==0: proj -> fp32 [row*VV + n].
// ---------------------------------------------------------------------------
template <int OUT_BF16>
__global__ __launch_bounds__(512)
void gemm_kernel(const bf16* __restrict__ A, const float* __restrict__ W,
                 const float* __restrict__ bias0, const float* __restrict__ bias1,
                 void* __restrict__ out, int t0, int NCOL) {
  __shared__ bf16x8 alds[4096];   // 128 rows x 32 granules(16B)
  __shared__ bf16x8 blds[4096];
  const int tid = threadIdx.x, w = tid >> 6, l = tid & 63, lg = l >> 4, ln = l & 15;
  const int wm = w & 1, wn = w >> 1;
  const int R0 = blockIdx.x * 128, N0 = blockIdx.y * 128;
  {
    const int row = tid >> 2, seg = tid & 3;   // 4 thr/row, 64 cols each
    const bf16* asrc;
    if (OUT_BF16) {
      const int R = R0 + row;
      asrc = A + ((size_t)(R >> 6) * SS + t0 + (R & 63)) * HH + seg * 64;
    } else {
      asrc = A + ((size_t)R0 + row) * HH + seg * 64;
    }
    #pragma unroll
    for (int k = 0; k < 8; ++k) {
      const int g = seg * 8 + k;
      alds[row * 32 + (g ^ (row & 7))] = *(const bf16x8*)(asrc + k * 8);
    }
    const float* bsrc = W + (size_t)(N0 + row) * HH + seg * 64;
    #pragma unroll
    for (int k = 0; k < 8; ++k) {
      const int g = seg * 8 + k;
      blds[row * 32 + (g ^ (row & 7))] = cvt8(bsrc + k * 8);
    }
  }
  __syncthreads();
  f32x4 acc[4][2] = {};
  #pragma unroll
  for (int kc = 0; kc < 8; ++kc) {
    bf16x8 bfr[2];
    #pragma unroll
    for (int nt = 0; nt < 2; ++nt) {
      const int row = wn * 32 + nt * 16 + ln;
      bfr[nt] = blds[row * 32 + ((kc * 4 + lg) ^ (row & 7))];
    }
    #pragma unroll
    for (int mt = 0; mt < 4; ++mt) {
      const int row = wm * 64 + mt * 16 + ln;
      bf16x8 a = alds[row * 32 + ((kc * 4 + lg) ^ (row & 7))];
      #pragma unroll
      for (int nt = 0; nt < 2; ++nt)
        acc[mt][nt] = __builtin_amdgcn_mfma_f32_16x16x32_bf16(a, bfr[nt], acc[mt][nt], 0, 0, 0);
    }
  }
  #pragma unroll
  for (int nt = 0; nt < 2; ++nt) {
    const int n = N0 + wn * 32 + nt * 16 + ln;
    const float bv = bias0[n] + (bias1 ? bias1[n] : 0.f);
    const int col = OUT_BF16 ? ((n & 255) * 4 + (n >> 8)) : n;
    #pragma unroll
    for (int mt = 0; mt < 4; ++mt)
      #pragma unroll
      for (int r = 0; r < 4; ++r) {
        const size_t row = (size_t)R0 + wm * 64 + mt * 16 + lg * 4 + r;
        if (OUT_BF16) ((bf16*)out)[row * NCOL + col] = (bf16)(acc[mt][nt][r] + bv);
        else          ((float*)out)[row * NCOL + col] = acc[mt][nt][r] + bv;
      }
  }
}

extern "C" void kernel_launch(void* const* d_in, const int* in_sizes, int n_in,
                              void* d_out, int out_size, void* d_ws, size_t ws_size,
                              hipStream_t stream) {
  const int*   x   = (const int*)d_in[0];
  const float* emb = (const float*)d_in[1];
  const float* Wi0 = (const float*)d_in[2];
  const float* bi0 = (const float*)d_in[3];
  const float* Wh0 = (const float*)d_in[4];
  const float* bh0 = (const float*)d_in[5];
  const float* Wi1 = (const float*)d_in[6];
  const float* bi1 = (const float*)d_in[7];
  const float* Wh1 = (const float*)d_in[8];
  const float* bh1 = (const float*)d_in[9];
  const float* Wg  = (const float*)d_in[10];
  const float* bg  = (const float*)d_in[11];

  // ws: [flag 256B][table bf16 256KB][wbuf0 512KB][wbuf1 512KB][hreg bf16 128MB]
  char* ws = (char*)d_ws;
  int* flag = (int*)ws;
  unsigned short* table = (unsigned short*)(ws + 256);
  bf16x8* wb0 = (bf16x8*)(ws + 256 + 262144);
  bf16x8* wb1 = (bf16x8*)(ws + 256 + 262144 + 524288);
  bf16* hreg = (bf16*)(ws + 256 + 262144 + 524288 + 524288);
  const size_t need = 256 + 262144 + 524288 + 524288
                    + (size_t)BB * SS * HH * sizeof(bf16);
  if (ws_size < need) return;

  // d_out as scratch until proj: [xg slice 67.1MB][cws 512KB]
  unsigned short* xg = (unsigned short*)d_out;
  float* cws = (float*)((char*)d_out + (size_t)BB * TSL * G4H * sizeof(bf16));

  (void)hipMemsetAsync(flag, 0, sizeof(int), stream);
  detect_kernel<<<dim3(8), dim3(256), 0, stream>>>(x, flag);
  table_kernel<<<dim3(4, 128), dim3(256), 0, stream>>>(emb, Wi0, bi0, bh0, table);
  wprep_kernel<<<dim3(128, 2), dim3(256), 0, stream>>>(Wh0, Wh1, wb0, wb1);
  rec0_kernel<<<dim3(BB / 16), dim3(512), 0, stream>>>(x, flag, wb0, table, hreg);
  for (int s = 0; s < NSEG; ++s) {
    const int t0 = s * TSL;
    gemm_kernel<1><<<dim3(BB * TSL / 128, G4H / 128), dim3(512), 0, stream>>>(
        hreg, Wi1, bi1, bh1, xg, t0, G4H);
    rec1_kernel<<<dim3(BB / 16), dim3(512), 0, stream>>>(xg, wb1, hreg, cws, t0);
  }
  gemm_kernel<0><<<dim3(BB * SS / 128, VV / 128), dim3(512), 0, stream>>>(
      hreg, Wg, bg, nullptr, d_out, 0, VV);
}